// Round 19
// baseline (62.260 us; speedup 1.0000x reference)
//
#include <hip/hip_runtime.h>
#include <hip/hip_bf16.h>

#define BB 4
#define NN 2048
#define FIN 128
#define NH 4
#define DH 32
#define NS 0.2f

typedef unsigned int u32;
typedef unsigned short u16;
typedef unsigned long long u64;
typedef __attribute__((ext_vector_type(8))) short short8;
typedef __attribute__((ext_vector_type(4))) float f32x4;
typedef __attribute__((ext_vector_type(4))) unsigned int u32x4;

// ws float offsets
#define OFF_ES   0         // [16][2048] f32
#define OFF_PQ   32768     // [16][2048] u32 (bf16 Q hi | bf16 P lo)
#define OFF_HT   65536     // u16 [16][32][2048] = 524288 floats
#define OFF_BITS 589824    // u32 bitsT[4][64][2048] = 524288 u32

__device__ __forceinline__ u16 f2bf_rne(float f) {
  unsigned u = __float_as_uint(f);
  return (u16)((u + 0x7fffu + ((u >> 16) & 1u)) >> 16);
}

__device__ __forceinline__ int bitmask(u32 w, int e) {
#if __has_builtin(__builtin_amdgcn_sbfe)
  return __builtin_amdgcn_sbfe((int)w, e, 1);     // v_bfe_i32: 0 or -1
#else
  return ((int)(w << (31 - e))) >> 31;
#endif
}

// Counted vmcnt wait + scheduler fence (T4; rule #18 requires the fence).
template<int N> __device__ __forceinline__ void vmwait() {
  asm volatile("s_waitcnt vmcnt(%0)" :: "n"(N) : "memory");
  __builtin_amdgcn_sched_barrier(0);
}
// Inline-asm loads: all in-loop VMEM goes through these so vmcnt counts are exact.
__device__ __forceinline__ u32x4 gld4(const void* p) {
  u32x4 r;
  asm volatile("global_load_dwordx4 %0, %1, off" : "=v"(r) : "v"(p));
  return r;
}
__device__ __forceinline__ u32 gld1(const void* p) {
  u32 r;
  asm volatile("global_load_dword %0, %1, off" : "=v"(r) : "v"(p));
  return r;
}

// ---------------- K0: pack adj -> TRANSPOSED bitmask bitsT[b][word][i] ------
__global__ __launch_bounds__(256) void k_pack(const int* __restrict__ adj,
                                              u32* __restrict__ bitsT) {
  __shared__ u32 tile[64][4];   // [word][row-in-block], 1 KB
  const int row0 = blockIdx.x * 4;           // 4 consecutive rows, same b
  const int wv = threadIdx.x >> 6;           // wave = row-in-block
  const int lane = threadIdx.x & 63;
  const int b = row0 >> 11, n0 = row0 & (NN - 1);
  const int* src = adj + (size_t)(row0 + wv) * NN;
#pragma unroll 8
  for (int it = 0; it < 32; ++it) {
    const u64 m = __ballot(src[it * 64 + lane] != 0);
    if (lane == 0) {
      tile[2 * it][wv] = (u32)m;
      tile[2 * it + 1][wv] = (u32)(m >> 32);
    }
  }
  __syncthreads();
  const int word = threadIdx.x >> 2, r = threadIdx.x & 3;
  bitsT[(size_t)b * 64 * NN + (size_t)word * NN + n0 + r] = tile[word][r];
}

// ---------------- K1: projection + e_src + P/Q tables + bf16 hT -------------
__global__ __launch_bounds__(256) void k_proj(
    const float* __restrict__ x, const float* __restrict__ W,
    const float* __restrict__ a, u16* __restrict__ hT,
    float* __restrict__ e_src, u32* __restrict__ PQ) {
  __shared__ float Ws[FIN * 128];
  const int tid = threadIdx.x;
  const int f = tid & 127, g = tid >> 7;
  const float4* Wg4 = (const float4*)W;
  float4* Ws4 = (float4*)Ws;
#pragma unroll
  for (int t = 0; t < 16; ++t) Ws4[t * 256 + tid] = Wg4[t * 256 + tid];
  __syncthreads();

  const int rb = blockIdx.x * 16 + g * 8;
  const int head = f >> 5, d = f & 31;
  const int b = rb >> 11, n0 = rb & (NN - 1);
  const int bh = b * NH + head;
  const float a_s = a[head * (2 * DH) + d];
  const float a_d = a[head * (2 * DH) + DH + d];

  float acc[8];
#pragma unroll
  for (int r = 0; r < 8; ++r) acc[r] = 0.f;

  const float* xb = x + (size_t)rb * FIN;  // wave-uniform -> s_loads
  for (int k = 0; k < FIN; ++k) {
    const float wv = Ws[k * 128 + f];
#pragma unroll
    for (int r = 0; r < 8; ++r) acc[r] = fmaf(wv, xb[r * FIN + k], acc[r]);
  }

  u16 hs[8];
#pragma unroll
  for (int r = 0; r < 8; ++r) hs[r] = f2bf_rne(acc[r]);
  u16* dst = hT + ((size_t)bh * DH + d) * NN + n0;
  *(int4*)dst = *(int4*)&hs[0];

#pragma unroll
  for (int r = 0; r < 8; ++r) {
    float s1 = acc[r] * a_s;
    float s2 = acc[r] * a_d;
#pragma unroll
    for (int off = 16; off >= 1; off >>= 1) {
      s1 += __shfl_xor(s1, off);
      s2 += __shfl_xor(s2, off);
    }
    if (d == 0) {
      e_src[(size_t)bh * NN + n0 + r] = s1;
      const u32 pb = f2bf_rne(__expf(s2));        // P = exp(e_dst)
      const u32 qb = f2bf_rne(__expf(NS * s2));   // Q = exp(0.2 e_dst)
      PQ[(size_t)bh * NN + n0 + r] = (qb << 16) | pb;
    }
  }
}

// ---------------- K2: 32-row tiles + forced 2-deep vmcnt pipeline -----------
// grid 1024 = 16 bh x 64 it-tiles -> 4 blocks/CU (4 waves/SIMD). 4 waves =
// 4 j-quarters; 2 row-sets/lane. 6 inline-asm loads/chunk; counted vmcnt(12)
// keeps 2 chunks in flight (T4). 3-slot rotation, all indices compile-time.
__global__ __launch_bounds__(256, 4) void k_attn(
    const u16* __restrict__ hT, const float* __restrict__ e_src,
    const u32* __restrict__ PQv, const u32* __restrict__ bitsT,
    float* __restrict__ out) {
  __shared__ float part[4][32][33];
  __shared__ float sp[4][2][16];

  const int bid = blockIdx.x;          // bh*64 + it
  const int bh = bid >> 6;
  const int it = bid & 63;
  const int b = bh >> 2, head = bh & 3;

  const int w = threadIdx.x >> 6;      // j-quarter
  const int lane = threadIdx.x & 63;
  const int lg = lane >> 4, lm = lane & 15;

  const int i0 = it * 32 + lm;
  const float es0 = e_src[(size_t)bh * NN + i0];
  const float es1 = e_src[(size_t)bh * NN + i0 + 16];
  const float A0 = __expf(es0), B0 = __expf(NS * es0);
  const float A1 = __expf(es1), B1 = __expf(NS * es1);
  // w_ij = exp(lrelu(es+ed)) = max(A_i*P_j, B_i*Q_j)   (exp monotone, exact)

  const int jwbase = w * 512;
  const u32* PQb = PQv + (size_t)bh * NN + jwbase;
  const u16* hb0 = hT + ((size_t)bh * DH + lm) * NN + jwbase;
  const u16* hb1 = hT + ((size_t)bh * DH + 16 + lm) * NN + jwbase;
  // bitsT[b][word][i]: words w*16+t; element index = row i
  const u32* btb = bitsT + (size_t)b * 64 * NN + (size_t)(w * 16) * NN + it * 32 + lm;
  const int shamt = lg * 8;
  const int jb = lg * 8;

  short8 ones;
#pragma unroll
  for (int e = 0; e < 8; ++e) ones[e] = (short)0x3F80;  // bf16 1.0

  f32x4 acc00 = {0,0,0,0}, acc01 = {0,0,0,0};
  f32x4 acc10 = {0,0,0,0}, acc11 = {0,0,0,0};
  f32x4 accS0 = {0,0,0,0}, accS1 = {0,0,0,0};

  // 3-slot register pipeline (depth 2; all indices compile-time under unroll)
  u32x4 pqa_[3], pqb_[3], h0_[3], h1_[3];
  u32 b0_[3], b1_[3];

#define ISSUE(tt, s) do { \
    const int jjI = (tt) * 32 + jb; \
    h0_[s]  = gld4(hb0 + jjI); \
    h1_[s]  = gld4(hb1 + jjI); \
    pqa_[s] = gld4(PQb + jjI); \
    pqb_[s] = gld4(PQb + jjI + 4); \
    const u32* bw_ = btb + (size_t)(tt) * NN; \
    b0_[s] = gld1(bw_); \
    b1_[s] = gld1(bw_ + 16); \
  } while (0)

#define COMPUTE(s) do { \
    const u32x4 pqa = pqa_[s]; \
    const u32x4 pqb = pqb_[s]; \
    const short8 hv0 = __builtin_bit_cast(short8, h0_[s]); \
    const short8 hv1 = __builtin_bit_cast(short8, h1_[s]); \
    const u32 wsh0 = b0_[s] >> shamt; \
    const u32 wsh1 = b1_[s] >> shamt; \
    short8 af0, af1; \
    _Pragma("unroll") \
    for (int e = 0; e < 8; ++e) { \
      const u32 pq = (e < 4) ? pqa[e] : pqb[e - 4]; \
      const float Pf = __uint_as_float(pq << 16); \
      const float Qf = __uint_as_float(pq & 0xffff0000u); \
      float w0 = fmaxf(A0 * Pf, B0 * Qf); \
      float w1 = fmaxf(A1 * Pf, B1 * Qf); \
      w0 = __int_as_float(__float_as_int(w0) & bitmask(wsh0, e)); \
      w1 = __int_as_float(__float_as_int(w1) & bitmask(wsh1, e)); \
      af0[e] = (short)__builtin_bit_cast(unsigned short, __float2bfloat16(w0)); \
      af1[e] = (short)__builtin_bit_cast(unsigned short, __float2bfloat16(w1)); \
    } \
    acc00 = __builtin_amdgcn_mfma_f32_16x16x32_bf16(af0, hv0, acc00, 0, 0, 0); \
    acc01 = __builtin_amdgcn_mfma_f32_16x16x32_bf16(af0, hv1, acc01, 0, 0, 0); \
    acc10 = __builtin_amdgcn_mfma_f32_16x16x32_bf16(af1, hv0, acc10, 0, 0, 0); \
    acc11 = __builtin_amdgcn_mfma_f32_16x16x32_bf16(af1, hv1, acc11, 0, 0, 0); \
    accS0 = __builtin_amdgcn_mfma_f32_16x16x32_bf16(af0, ones, accS0, 0, 0, 0); \
    accS1 = __builtin_amdgcn_mfma_f32_16x16x32_bf16(af1, ones, accS1, 0, 0, 0); \
  } while (0)

  // drain pre-loop loads so vmcnt counts only pipeline loads
  vmwait<0>();
  ISSUE(0, 0);
  ISSUE(1, 1);
  // steady state: issue t+2, wait for chunk t (2 chunks x 6 loads in flight)
#pragma unroll
  for (int t = 0; t < 14; ++t) {
    ISSUE(t + 2, (t + 2) % 3);
    vmwait<12>();
    COMPUTE(t % 3);
  }
  vmwait<6>(); COMPUTE(14 % 3);   // chunk 14
  vmwait<0>(); COMPUTE(15 % 3);   // chunk 15

#undef ISSUE
#undef COMPUTE

#pragma unroll
  for (int r = 0; r < 4; ++r) {
    const int rl = lg * 4 + r;   // C row = (lane>>4)*4 + reg
    part[w][rl][lm]           = acc00[r];
    part[w][rl][16 + lm]      = acc01[r];
    part[w][16 + rl][lm]      = acc10[r];
    part[w][16 + rl][16 + lm] = acc11[r];
  }
  if (lm == 0) {
#pragma unroll
    for (int r = 0; r < 4; ++r) {
      sp[w][0][lg * 4 + r] = accS0[r];  // every col holds the row-sum
      sp[w][1][lg * 4 + r] = accS1[r];
    }
  }
  __syncthreads();

  const int tid = threadIdx.x;
#pragma unroll
  for (int t = 0; t < 4; ++t) {
    const int idx = t * 256 + tid;     // 32 rows x 32 d
    const int row = idx >> 5, d = idx & 31;
    const float v = part[0][row][d] + part[1][row][d] +
                    part[2][row][d] + part[3][row][d];
    const float s = sp[0][row >> 4][row & 15] + sp[1][row >> 4][row & 15] +
                    sp[2][row >> 4][row & 15] + sp[3][row >> 4][row & 15];
    const float o = v / s;
    const int n = it * 32 + row;
    out[((size_t)b * NN + n) * 128 + head * 32 + d] =
        o > 0.f ? o : (__expf(o) - 1.f);
  }
}

extern "C" void kernel_launch(void* const* d_in, const int* in_sizes, int n_in,
                              void* d_out, int out_size, void* d_ws, size_t ws_size,
                              hipStream_t stream) {
  const float* x = (const float*)d_in[0];
  const int* adj = (const int*)d_in[1];
  const float* W = (const float*)d_in[2];
  const float* a = (const float*)d_in[3];
  float* out = (float*)d_out;
  float* ws = (float*)d_ws;

  float* e_src = ws + OFF_ES;
  u32* PQv = (u32*)(ws + OFF_PQ);
  u16* hT = (u16*)(ws + OFF_HT);
  u32* bitsT = (u32*)(ws + OFF_BITS);

  k_pack<<<(BB * NN) / 4, 256, 0, stream>>>(adj, bitsT);
  k_proj<<<(BB * NN) / 16, 256, 0, stream>>>(x, W, a, hT, e_src, PQv);
  k_attn<<<BB * NH * 64, 256, 0, stream>>>(hT, e_src, PQv, bitsT, out);
}

// Round 20
// 60.807 us; speedup vs baseline: 1.0239x; 1.0239x over previous
//
#include <hip/hip_runtime.h>
#include <hip/hip_bf16.h>

#define BB 4
#define NN 2048
#define FIN 128
#define NH 4
#define DH 32
#define NS 0.2f

typedef unsigned int u32;
typedef unsigned short u16;
typedef unsigned long long u64;
typedef __attribute__((ext_vector_type(8))) short short8;
typedef __attribute__((ext_vector_type(4))) float f32x4;
typedef __attribute__((ext_vector_type(4))) unsigned int u32x4;

// ws float offsets
#define OFF_ES   0         // [16][2048] f32
#define OFF_PQ   32768     // [16][2048] u32 (bf16 Q hi | bf16 P lo)
#define OFF_HT   65536     // u16 [16][32][2048] = 524288 floats
#define OFF_BITS 589824    // u32 bitsT[4][64][2048] = 524288 u32

__device__ __forceinline__ u16 f2bf_rne(float f) {
  unsigned u = __float_as_uint(f);
  return (u16)((u + 0x7fffu + ((u >> 16) & 1u)) >> 16);
}

__device__ __forceinline__ int bitmask(u32 w, int e) {
#if __has_builtin(__builtin_amdgcn_sbfe)
  return __builtin_amdgcn_sbfe((int)w, e, 1);     // v_bfe_i32: 0 or -1
#else
  return ((int)(w << (31 - e))) >> 31;
#endif
}

// Counted vmcnt wait + scheduler fence (T4; rule #18 requires the fence).
template<int N> __device__ __forceinline__ void vmwait() {
  asm volatile("s_waitcnt vmcnt(%0)" :: "n"(N) : "memory");
  __builtin_amdgcn_sched_barrier(0);
}
// Inline-asm loads: all in-loop VMEM goes through these so vmcnt counts are exact.
__device__ __forceinline__ u32x4 gld4(const void* p) {
  u32x4 r;
  asm volatile("global_load_dwordx4 %0, %1, off" : "=v"(r) : "v"(p));
  return r;
}
__device__ __forceinline__ u32 gld1(const void* p) {
  u32 r;
  asm volatile("global_load_dword %0, %1, off" : "=v"(r) : "v"(p));
  return r;
}

// ---------------- K0: pack adj -> TRANSPOSED bitmask bitsT[b][word][i] ------
__global__ __launch_bounds__(256) void k_pack(const int* __restrict__ adj,
                                              u32* __restrict__ bitsT) {
  __shared__ u32 tile[64][4];   // [word][row-in-block], 1 KB
  const int row0 = blockIdx.x * 4;           // 4 consecutive rows, same b
  const int wv = threadIdx.x >> 6;           // wave = row-in-block
  const int lane = threadIdx.x & 63;
  const int b = row0 >> 11, n0 = row0 & (NN - 1);
  const int* src = adj + (size_t)(row0 + wv) * NN;
#pragma unroll 8
  for (int it = 0; it < 32; ++it) {
    const u64 m = __ballot(src[it * 64 + lane] != 0);
    if (lane == 0) {
      tile[2 * it][wv] = (u32)m;
      tile[2 * it + 1][wv] = (u32)(m >> 32);
    }
  }
  __syncthreads();
  const int word = threadIdx.x >> 2, r = threadIdx.x & 3;
  bitsT[(size_t)b * 64 * NN + (size_t)word * NN + n0 + r] = tile[word][r];
}

// ---------------- K1: projection + e_src + P/Q tables + bf16 hT -------------
__global__ __launch_bounds__(256) void k_proj(
    const float* __restrict__ x, const float* __restrict__ W,
    const float* __restrict__ a, u16* __restrict__ hT,
    float* __restrict__ e_src, u32* __restrict__ PQ) {
  __shared__ float Ws[FIN * 128];
  const int tid = threadIdx.x;
  const int f = tid & 127, g = tid >> 7;
  const float4* Wg4 = (const float4*)W;
  float4* Ws4 = (float4*)Ws;
#pragma unroll
  for (int t = 0; t < 16; ++t) Ws4[t * 256 + tid] = Wg4[t * 256 + tid];
  __syncthreads();

  const int rb = blockIdx.x * 16 + g * 8;
  const int head = f >> 5, d = f & 31;
  const int b = rb >> 11, n0 = rb & (NN - 1);
  const int bh = b * NH + head;
  const float a_s = a[head * (2 * DH) + d];
  const float a_d = a[head * (2 * DH) + DH + d];

  float acc[8];
#pragma unroll
  for (int r = 0; r < 8; ++r) acc[r] = 0.f;

  const float* xb = x + (size_t)rb * FIN;  // wave-uniform -> s_loads
  for (int k = 0; k < FIN; ++k) {
    const float wv = Ws[k * 128 + f];
#pragma unroll
    for (int r = 0; r < 8; ++r) acc[r] = fmaf(wv, xb[r * FIN + k], acc[r]);
  }

  u16 hs[8];
#pragma unroll
  for (int r = 0; r < 8; ++r) hs[r] = f2bf_rne(acc[r]);
  u16* dst = hT + ((size_t)bh * DH + d) * NN + n0;
  *(int4*)dst = *(int4*)&hs[0];

#pragma unroll
  for (int r = 0; r < 8; ++r) {
    float s1 = acc[r] * a_s;
    float s2 = acc[r] * a_d;
#pragma unroll
    for (int off = 16; off >= 1; off >>= 1) {
      s1 += __shfl_xor(s1, off);
      s2 += __shfl_xor(s2, off);
    }
    if (d == 0) {
      e_src[(size_t)bh * NN + n0 + r] = s1;
      const u32 pb = f2bf_rne(__expf(s2));        // P = exp(e_dst)
      const u32 qb = f2bf_rne(__expf(NS * s2));   // Q = exp(0.2 e_dst)
      PQ[(size_t)bh * NN + n0 + r] = (qb << 16) | pb;
    }
  }
}

// ---------------- K2: 64-row tiles + forced 2-deep vmcnt pipeline + T5 ------
// grid 512 = 16 bh x 32 it-tiles; 4 waves = 4 j-quarters; 4 row-sets/lane.
// All in-loop loads are inline-asm; counted vmcnt(16) keeps 2 chunks of loads
// in flight (T4). setprio(1) wraps the MFMA cluster (T5: pays when waves are
// at different pipeline phases -- no barriers in the main loop).
__global__ __launch_bounds__(256, 2) void k_attn(
    const u16* __restrict__ hT, const float* __restrict__ e_src,
    const u32* __restrict__ PQv, const u32* __restrict__ bitsT,
    float* __restrict__ out) {
  __shared__ float part[4][64][33];
  __shared__ float sp[4][4][16];

  const int bid = blockIdx.x;          // bh*32 + it
  const int bh = bid >> 5;
  const int it = bid & 31;
  const int b = bh >> 2, head = bh & 3;

  const int w = threadIdx.x >> 6;      // j-quarter
  const int lane = threadIdx.x & 63;
  const int lg = lane >> 4, lm = lane & 15;

  float A[4], B[4];
#pragma unroll
  for (int rs = 0; rs < 4; ++rs) {
    const float es = e_src[(size_t)bh * NN + it * 64 + rs * 16 + lm];
    A[rs] = __expf(es);
    B[rs] = __expf(NS * es);
  }
  // w_ij = exp(lrelu(es+ed)) = max(A_i*P_j, B_i*Q_j)   (exp monotone, exact)

  const int jwbase = w * 512;
  const u32* PQb = PQv + (size_t)bh * NN + jwbase;
  const u16* hb0 = hT + ((size_t)bh * DH + lm) * NN + jwbase;
  const u16* hb1 = hT + ((size_t)bh * DH + 16 + lm) * NN + jwbase;
  const u32* btb = bitsT + (size_t)b * 64 * NN + (size_t)(w * 16) * NN + it * 64 + lm;
  const int shamt = lg * 8;
  const int jb = lg * 8;

  short8 ones;
#pragma unroll
  for (int e = 0; e < 8; ++e) ones[e] = (short)0x3F80;  // bf16 1.0

  f32x4 acc00 = {0,0,0,0}, acc01 = {0,0,0,0};
  f32x4 acc10 = {0,0,0,0}, acc11 = {0,0,0,0};
  f32x4 acc20 = {0,0,0,0}, acc21 = {0,0,0,0};
  f32x4 acc30 = {0,0,0,0}, acc31 = {0,0,0,0};
  f32x4 accS0 = {0,0,0,0}, accS1 = {0,0,0,0};
  f32x4 accS2 = {0,0,0,0}, accS3 = {0,0,0,0};

  // 4-slot register pipeline (all indices compile-time under full unroll)
  u32x4 pqa_[4], pqb_[4], h0_[4], h1_[4];
  u32 b0_[4], b1_[4], b2_[4], b3_[4];

#define ISSUE(tt, s) do { \
    const int jjI = (tt) * 32 + jb; \
    h0_[s]  = gld4(hb0 + jjI); \
    h1_[s]  = gld4(hb1 + jjI); \
    pqa_[s] = gld4(PQb + jjI); \
    pqb_[s] = gld4(PQb + jjI + 4); \
    const u32* bw_ = btb + (size_t)(tt) * NN; \
    b0_[s] = gld1(bw_); \
    b1_[s] = gld1(bw_ + 16); \
    b2_[s] = gld1(bw_ + 32); \
    b3_[s] = gld1(bw_ + 48); \
  } while (0)

#define COMPUTE(s) do { \
    const u32x4 pqa = pqa_[s]; \
    const u32x4 pqb = pqb_[s]; \
    const short8 hv0 = __builtin_bit_cast(short8, h0_[s]); \
    const short8 hv1 = __builtin_bit_cast(short8, h1_[s]); \
    const u32 wsh0 = b0_[s] >> shamt; \
    const u32 wsh1 = b1_[s] >> shamt; \
    const u32 wsh2 = b2_[s] >> shamt; \
    const u32 wsh3 = b3_[s] >> shamt; \
    short8 af0, af1, af2, af3; \
    _Pragma("unroll") \
    for (int e = 0; e < 8; ++e) { \
      const u32 pq = (e < 4) ? pqa[e] : pqb[e - 4]; \
      const float Pf = __uint_as_float(pq << 16); \
      const float Qf = __uint_as_float(pq & 0xffff0000u); \
      float w0 = fmaxf(A[0] * Pf, B[0] * Qf); \
      float w1 = fmaxf(A[1] * Pf, B[1] * Qf); \
      float w2 = fmaxf(A[2] * Pf, B[2] * Qf); \
      float w3 = fmaxf(A[3] * Pf, B[3] * Qf); \
      w0 = __int_as_float(__float_as_int(w0) & bitmask(wsh0, e)); \
      w1 = __int_as_float(__float_as_int(w1) & bitmask(wsh1, e)); \
      w2 = __int_as_float(__float_as_int(w2) & bitmask(wsh2, e)); \
      w3 = __int_as_float(__float_as_int(w3) & bitmask(wsh3, e)); \
      af0[e] = (short)__builtin_bit_cast(unsigned short, __float2bfloat16(w0)); \
      af1[e] = (short)__builtin_bit_cast(unsigned short, __float2bfloat16(w1)); \
      af2[e] = (short)__builtin_bit_cast(unsigned short, __float2bfloat16(w2)); \
      af3[e] = (short)__builtin_bit_cast(unsigned short, __float2bfloat16(w3)); \
    } \
    __builtin_amdgcn_s_setprio(1); \
    acc00 = __builtin_amdgcn_mfma_f32_16x16x32_bf16(af0, hv0, acc00, 0, 0, 0); \
    acc01 = __builtin_amdgcn_mfma_f32_16x16x32_bf16(af0, hv1, acc01, 0, 0, 0); \
    acc10 = __builtin_amdgcn_mfma_f32_16x16x32_bf16(af1, hv0, acc10, 0, 0, 0); \
    acc11 = __builtin_amdgcn_mfma_f32_16x16x32_bf16(af1, hv1, acc11, 0, 0, 0); \
    acc20 = __builtin_amdgcn_mfma_f32_16x16x32_bf16(af2, hv0, acc20, 0, 0, 0); \
    acc21 = __builtin_amdgcn_mfma_f32_16x16x32_bf16(af2, hv1, acc21, 0, 0, 0); \
    acc30 = __builtin_amdgcn_mfma_f32_16x16x32_bf16(af3, hv0, acc30, 0, 0, 0); \
    acc31 = __builtin_amdgcn_mfma_f32_16x16x32_bf16(af3, hv1, acc31, 0, 0, 0); \
    accS0 = __builtin_amdgcn_mfma_f32_16x16x32_bf16(af0, ones, accS0, 0, 0, 0); \
    accS1 = __builtin_amdgcn_mfma_f32_16x16x32_bf16(af1, ones, accS1, 0, 0, 0); \
    accS2 = __builtin_amdgcn_mfma_f32_16x16x32_bf16(af2, ones, accS2, 0, 0, 0); \
    accS3 = __builtin_amdgcn_mfma_f32_16x16x32_bf16(af3, ones, accS3, 0, 0, 0); \
    __builtin_amdgcn_s_setprio(0); \
  } while (0)

  // drain pre-loop loads so vmcnt counts only pipeline loads
  vmwait<0>();
  ISSUE(0, 0);
  ISSUE(1, 1);
  // steady state: issue t+2, wait for chunk t (2 chunks x 8 loads in flight)
#pragma unroll
  for (int t = 0; t < 12; ++t) {
    ISSUE(t + 2, (t + 2) & 3);
    vmwait<16>();
    COMPUTE(t & 3);
  }
  ISSUE(14, 2); vmwait<16>(); COMPUTE(0);
  ISSUE(15, 3); vmwait<16>(); COMPUTE(1);
  vmwait<8>();  COMPUTE(2);
  vmwait<0>();  COMPUTE(3);

#undef ISSUE
#undef COMPUTE

#pragma unroll
  for (int r = 0; r < 4; ++r) {
    const int rl = lg * 4 + r;   // C row = (lane>>4)*4 + reg
    part[w][rl][lm]           = acc00[r];
    part[w][rl][16 + lm]      = acc01[r];
    part[w][16 + rl][lm]      = acc10[r];
    part[w][16 + rl][16 + lm] = acc11[r];
    part[w][32 + rl][lm]      = acc20[r];
    part[w][32 + rl][16 + lm] = acc21[r];
    part[w][48 + rl][lm]      = acc30[r];
    part[w][48 + rl][16 + lm] = acc31[r];
  }
  if (lm == 0) {
#pragma unroll
    for (int r = 0; r < 4; ++r) {
      sp[w][0][lg * 4 + r] = accS0[r];
      sp[w][1][lg * 4 + r] = accS1[r];
      sp[w][2][lg * 4 + r] = accS2[r];
      sp[w][3][lg * 4 + r] = accS3[r];
    }
  }
  __syncthreads();

  const int tid = threadIdx.x;
#pragma unroll
  for (int t = 0; t < 8; ++t) {
    const int idx = t * 256 + tid;     // 64 rows x 32 d
    const int row = idx >> 5, d = idx & 31;
    const float v = part[0][row][d] + part[1][row][d] +
                    part[2][row][d] + part[3][row][d];
    const float s = sp[0][row >> 4][row & 15] + sp[1][row >> 4][row & 15] +
                    sp[2][row >> 4][row & 15] + sp[3][row >> 4][row & 15];
    const float o = v / s;
    const int n = it * 64 + row;
    out[((size_t)b * NN + n) * 128 + head * 32 + d] =
        o > 0.f ? o : (__expf(o) - 1.f);
  }
}

extern "C" void kernel_launch(void* const* d_in, const int* in_sizes, int n_in,
                              void* d_out, int out_size, void* d_ws, size_t ws_size,
                              hipStream_t stream) {
  const float* x = (const float*)d_in[0];
  const int* adj = (const int*)d_in[1];
  const float* W = (const float*)d_in[2];
  const float* a = (const float*)d_in[3];
  float* out = (float*)d_out;
  float* ws = (float*)d_ws;

  float* e_src = ws + OFF_ES;
  u32* PQv = (u32*)(ws + OFF_PQ);
  u16* hT = (u16*)(ws + OFF_HT);
  u32* bitsT = (u32*)(ws + OFF_BITS);

  k_pack<<<(BB * NN) / 4, 256, 0, stream>>>(adj, bitsT);
  k_proj<<<(BB * NN) / 16, 256, 0, stream>>>(x, W, a, hT, e_src, PQv);
  k_attn<<<BB * NH * 32, 256, 0, stream>>>(hT, e_src, PQv, bitsT, out);
}

// Round 21
// 59.262 us; speedup vs baseline: 1.0506x; 1.0261x over previous
//
#include <hip/hip_runtime.h>
#include <hip/hip_bf16.h>

#define BB 4
#define NN 2048
#define FIN 128
#define NH 4
#define DH 32
#define NS 0.2f

typedef unsigned int u32;
typedef unsigned short u16;
typedef unsigned long long u64;
typedef __attribute__((ext_vector_type(8))) short short8;
typedef __attribute__((ext_vector_type(4))) float f32x4;
typedef __attribute__((ext_vector_type(4))) unsigned int u32x4;

// ws float offsets
#define OFF_ES   0         // [16][2048] f32
#define OFF_PQ   32768     // [16][2048] u32 (bf16 Q hi | bf16 P lo)
#define OFF_HT   65536     // u16 [16][32][2048] = 524288 floats
#define OFF_BITS 589824    // u32 bitsT[4][64][2048] = 524288 u32

__device__ __forceinline__ u16 f2bf_rne(float f) {
  unsigned u = __float_as_uint(f);
  return (u16)((u + 0x7fffu + ((u >> 16) & 1u)) >> 16);
}

__device__ __forceinline__ int bitmask(u32 w, int e) {
#if __has_builtin(__builtin_amdgcn_sbfe)
  return __builtin_amdgcn_sbfe((int)w, e, 1);     // v_bfe_i32: 0 or -1
#else
  return ((int)(w << (31 - e))) >> 31;
#endif
}

// Counted vmcnt wait + scheduler fence (T4; rule #18 requires the fence).
template<int N> __device__ __forceinline__ void vmwait() {
  asm volatile("s_waitcnt vmcnt(%0)" :: "n"(N) : "memory");
  __builtin_amdgcn_sched_barrier(0);
}
// Inline-asm loads: all in-loop VMEM goes through these so vmcnt counts are exact.
__device__ __forceinline__ u32x4 gld4(const void* p) {
  u32x4 r;
  asm volatile("global_load_dwordx4 %0, %1, off" : "=v"(r) : "v"(p));
  return r;
}
__device__ __forceinline__ u32 gld1(const void* p) {
  u32 r;
  asm volatile("global_load_dword %0, %1, off" : "=v"(r) : "v"(p));
  return r;
}

// ---------------- K0: pack adj -> TRANSPOSED bitmask bitsT[b][word][i] ------
__global__ __launch_bounds__(256) void k_pack(const int* __restrict__ adj,
                                              u32* __restrict__ bitsT) {
  __shared__ u32 tile[64][4];   // [word][row-in-block], 1 KB
  const int row0 = blockIdx.x * 4;           // 4 consecutive rows, same b
  const int wv = threadIdx.x >> 6;           // wave = row-in-block
  const int lane = threadIdx.x & 63;
  const int b = row0 >> 11, n0 = row0 & (NN - 1);
  const int* src = adj + (size_t)(row0 + wv) * NN;
#pragma unroll 8
  for (int it = 0; it < 32; ++it) {
    const u64 m = __ballot(src[it * 64 + lane] != 0);
    if (lane == 0) {
      tile[2 * it][wv] = (u32)m;
      tile[2 * it + 1][wv] = (u32)(m >> 32);
    }
  }
  __syncthreads();
  const int word = threadIdx.x >> 2, r = threadIdx.x & 3;
  bitsT[(size_t)b * 64 * NN + (size_t)word * NN + n0 + r] = tile[word][r];
}

// ---------------- K1: projection + e_src + P/Q tables + bf16 hT -------------
__global__ __launch_bounds__(256) void k_proj(
    const float* __restrict__ x, const float* __restrict__ W,
    const float* __restrict__ a, u16* __restrict__ hT,
    float* __restrict__ e_src, u32* __restrict__ PQ) {
  __shared__ float Ws[FIN * 128];
  const int tid = threadIdx.x;
  const int f = tid & 127, g = tid >> 7;
  const float4* Wg4 = (const float4*)W;
  float4* Ws4 = (float4*)Ws;
#pragma unroll
  for (int t = 0; t < 16; ++t) Ws4[t * 256 + tid] = Wg4[t * 256 + tid];
  __syncthreads();

  const int rb = blockIdx.x * 16 + g * 8;
  const int head = f >> 5, d = f & 31;
  const int b = rb >> 11, n0 = rb & (NN - 1);
  const int bh = b * NH + head;
  const float a_s = a[head * (2 * DH) + d];
  const float a_d = a[head * (2 * DH) + DH + d];

  float acc[8];
#pragma unroll
  for (int r = 0; r < 8; ++r) acc[r] = 0.f;

  const float* xb = x + (size_t)rb * FIN;  // wave-uniform -> s_loads
  for (int k = 0; k < FIN; ++k) {
    const float wv = Ws[k * 128 + f];
#pragma unroll
    for (int r = 0; r < 8; ++r) acc[r] = fmaf(wv, xb[r * FIN + k], acc[r]);
  }

  u16 hs[8];
#pragma unroll
  for (int r = 0; r < 8; ++r) hs[r] = f2bf_rne(acc[r]);
  u16* dst = hT + ((size_t)bh * DH + d) * NN + n0;
  *(int4*)dst = *(int4*)&hs[0];

#pragma unroll
  for (int r = 0; r < 8; ++r) {
    float s1 = acc[r] * a_s;
    float s2 = acc[r] * a_d;
#pragma unroll
    for (int off = 16; off >= 1; off >>= 1) {
      s1 += __shfl_xor(s1, off);
      s2 += __shfl_xor(s2, off);
    }
    if (d == 0) {
      e_src[(size_t)bh * NN + n0 + r] = s1;
      const u32 pb = f2bf_rne(__expf(s2));        // P = exp(e_dst)
      const u32 qb = f2bf_rne(__expf(NS * s2));   // Q = exp(0.2 e_dst)
      PQ[(size_t)bh * NN + n0 + r] = (qb << 16) | pb;
    }
  }
}

// ---------------- K2: 64-row tiles + forced 2-deep vmcnt pipeline -----------
// grid 512 = 16 bh x 32 it-tiles; 4 waves = 4 j-quarters; 4 row-sets/lane.
// All in-loop loads are inline-asm; counted vmcnt(16) keeps 2 chunks of loads
// in flight across compute (T4). Wave-private: no barriers in the main loop.
__global__ __launch_bounds__(256, 2) void k_attn(
    const u16* __restrict__ hT, const float* __restrict__ e_src,
    const u32* __restrict__ PQv, const u32* __restrict__ bitsT,
    float* __restrict__ out) {
  __shared__ float part[4][64][33];
  __shared__ float sp[4][4][16];

  const int bid = blockIdx.x;          // bh*32 + it
  const int bh = bid >> 5;
  const int it = bid & 31;
  const int b = bh >> 2, head = bh & 3;

  const int w = threadIdx.x >> 6;      // j-quarter
  const int lane = threadIdx.x & 63;
  const int lg = lane >> 4, lm = lane & 15;

  float A[4], B[4];
#pragma unroll
  for (int rs = 0; rs < 4; ++rs) {
    const float es = e_src[(size_t)bh * NN + it * 64 + rs * 16 + lm];
    A[rs] = __expf(es);
    B[rs] = __expf(NS * es);
  }
  // w_ij = exp(lrelu(es+ed)) = max(A_i*P_j, B_i*Q_j)   (exp monotone, exact)

  const int jwbase = w * 512;
  const u32* PQb = PQv + (size_t)bh * NN + jwbase;
  const u16* hb0 = hT + ((size_t)bh * DH + lm) * NN + jwbase;
  const u16* hb1 = hT + ((size_t)bh * DH + 16 + lm) * NN + jwbase;
  const u32* btb = bitsT + (size_t)b * 64 * NN + (size_t)(w * 16) * NN + it * 64 + lm;
  const int shamt = lg * 8;
  const int jb = lg * 8;

  short8 ones;
#pragma unroll
  for (int e = 0; e < 8; ++e) ones[e] = (short)0x3F80;  // bf16 1.0

  f32x4 acc00 = {0,0,0,0}, acc01 = {0,0,0,0};
  f32x4 acc10 = {0,0,0,0}, acc11 = {0,0,0,0};
  f32x4 acc20 = {0,0,0,0}, acc21 = {0,0,0,0};
  f32x4 acc30 = {0,0,0,0}, acc31 = {0,0,0,0};
  f32x4 accS0 = {0,0,0,0}, accS1 = {0,0,0,0};
  f32x4 accS2 = {0,0,0,0}, accS3 = {0,0,0,0};

  // 4-slot register pipeline (all indices compile-time under full unroll)
  u32x4 pqa_[4], pqb_[4], h0_[4], h1_[4];
  u32 b0_[4], b1_[4], b2_[4], b3_[4];

#define ISSUE(tt, s) do { \
    const int jjI = (tt) * 32 + jb; \
    pqa_[s] = gld4(PQb + jjI); \
    pqb_[s] = gld4(PQb + jjI + 4); \
    h0_[s]  = gld4(hb0 + jjI); \
    h1_[s]  = gld4(hb1 + jjI); \
    const u32* bw_ = btb + (size_t)(tt) * NN; \
    b0_[s] = gld1(bw_); \
    b1_[s] = gld1(bw_ + 16); \
    b2_[s] = gld1(bw_ + 32); \
    b3_[s] = gld1(bw_ + 48); \
  } while (0)

#define COMPUTE(s) do { \
    const u32x4 pqa = pqa_[s]; \
    const u32x4 pqb = pqb_[s]; \
    const short8 hv0 = __builtin_bit_cast(short8, h0_[s]); \
    const short8 hv1 = __builtin_bit_cast(short8, h1_[s]); \
    const u32 wsh0 = b0_[s] >> shamt; \
    const u32 wsh1 = b1_[s] >> shamt; \
    const u32 wsh2 = b2_[s] >> shamt; \
    const u32 wsh3 = b3_[s] >> shamt; \
    short8 af0, af1, af2, af3; \
    _Pragma("unroll") \
    for (int e = 0; e < 8; ++e) { \
      const u32 pq = (e < 4) ? pqa[e] : pqb[e - 4]; \
      const float Pf = __uint_as_float(pq << 16); \
      const float Qf = __uint_as_float(pq & 0xffff0000u); \
      float w0 = fmaxf(A[0] * Pf, B[0] * Qf); \
      float w1 = fmaxf(A[1] * Pf, B[1] * Qf); \
      float w2 = fmaxf(A[2] * Pf, B[2] * Qf); \
      float w3 = fmaxf(A[3] * Pf, B[3] * Qf); \
      w0 = __int_as_float(__float_as_int(w0) & bitmask(wsh0, e)); \
      w1 = __int_as_float(__float_as_int(w1) & bitmask(wsh1, e)); \
      w2 = __int_as_float(__float_as_int(w2) & bitmask(wsh2, e)); \
      w3 = __int_as_float(__float_as_int(w3) & bitmask(wsh3, e)); \
      af0[e] = (short)__builtin_bit_cast(unsigned short, __float2bfloat16(w0)); \
      af1[e] = (short)__builtin_bit_cast(unsigned short, __float2bfloat16(w1)); \
      af2[e] = (short)__builtin_bit_cast(unsigned short, __float2bfloat16(w2)); \
      af3[e] = (short)__builtin_bit_cast(unsigned short, __float2bfloat16(w3)); \
    } \
    acc00 = __builtin_amdgcn_mfma_f32_16x16x32_bf16(af0, hv0, acc00, 0, 0, 0); \
    acc01 = __builtin_amdgcn_mfma_f32_16x16x32_bf16(af0, hv1, acc01, 0, 0, 0); \
    acc10 = __builtin_amdgcn_mfma_f32_16x16x32_bf16(af1, hv0, acc10, 0, 0, 0); \
    acc11 = __builtin_amdgcn_mfma_f32_16x16x32_bf16(af1, hv1, acc11, 0, 0, 0); \
    acc20 = __builtin_amdgcn_mfma_f32_16x16x32_bf16(af2, hv0, acc20, 0, 0, 0); \
    acc21 = __builtin_amdgcn_mfma_f32_16x16x32_bf16(af2, hv1, acc21, 0, 0, 0); \
    acc30 = __builtin_amdgcn_mfma_f32_16x16x32_bf16(af3, hv0, acc30, 0, 0, 0); \
    acc31 = __builtin_amdgcn_mfma_f32_16x16x32_bf16(af3, hv1, acc31, 0, 0, 0); \
    accS0 = __builtin_amdgcn_mfma_f32_16x16x32_bf16(af0, ones, accS0, 0, 0, 0); \
    accS1 = __builtin_amdgcn_mfma_f32_16x16x32_bf16(af1, ones, accS1, 0, 0, 0); \
    accS2 = __builtin_amdgcn_mfma_f32_16x16x32_bf16(af2, ones, accS2, 0, 0, 0); \
    accS3 = __builtin_amdgcn_mfma_f32_16x16x32_bf16(af3, ones, accS3, 0, 0, 0); \
  } while (0)

  // drain any compiler-issued loads so vmcnt counts only pipeline loads
  vmwait<0>();
  ISSUE(0, 0);
  ISSUE(1, 1);
  // steady state: issue t+2, wait for chunk t (2 chunks x 8 loads in flight)
#pragma unroll
  for (int t = 0; t < 12; ++t) {
    ISSUE(t + 2, (t + 2) & 3);
    vmwait<16>();
    COMPUTE(t & 3);
  }
  ISSUE(14, 2); vmwait<16>(); COMPUTE(0);
  ISSUE(15, 3); vmwait<16>(); COMPUTE(1);
  vmwait<8>();  COMPUTE(2);
  vmwait<0>();  COMPUTE(3);

#undef ISSUE
#undef COMPUTE

#pragma unroll
  for (int r = 0; r < 4; ++r) {
    const int rl = lg * 4 + r;   // C row = (lane>>4)*4 + reg
    part[w][rl][lm]           = acc00[r];
    part[w][rl][16 + lm]      = acc01[r];
    part[w][16 + rl][lm]      = acc10[r];
    part[w][16 + rl][16 + lm] = acc11[r];
    part[w][32 + rl][lm]      = acc20[r];
    part[w][32 + rl][16 + lm] = acc21[r];
    part[w][48 + rl][lm]      = acc30[r];
    part[w][48 + rl][16 + lm] = acc31[r];
  }
  if (lm == 0) {
#pragma unroll
    for (int r = 0; r < 4; ++r) {
      sp[w][0][lg * 4 + r] = accS0[r];
      sp[w][1][lg * 4 + r] = accS1[r];
      sp[w][2][lg * 4 + r] = accS2[r];
      sp[w][3][lg * 4 + r] = accS3[r];
    }
  }
  __syncthreads();

  const int tid = threadIdx.x;
#pragma unroll
  for (int t = 0; t < 8; ++t) {
    const int idx = t * 256 + tid;     // 64 rows x 32 d
    const int row = idx >> 5, d = idx & 31;
    const float v = part[0][row][d] + part[1][row][d] +
                    part[2][row][d] + part[3][row][d];
    const float s = sp[0][row >> 4][row & 15] + sp[1][row >> 4][row & 15] +
                    sp[2][row >> 4][row & 15] + sp[3][row >> 4][row & 15];
    const float o = v / s;
    const int n = it * 64 + row;
    out[((size_t)b * NN + n) * 128 + head * 32 + d] =
        o > 0.f ? o : (__expf(o) - 1.f);
  }
}

extern "C" void kernel_launch(void* const* d_in, const int* in_sizes, int n_in,
                              void* d_out, int out_size, void* d_ws, size_t ws_size,
                              hipStream_t stream) {
  const float* x = (const float*)d_in[0];
  const int* adj = (const int*)d_in[1];
  const float* W = (const float*)d_in[2];
  const float* a = (const float*)d_in[3];
  float* out = (float*)d_out;
  float* ws = (float*)d_ws;

  float* e_src = ws + OFF_ES;
  u32* PQv = (u32*)(ws + OFF_PQ);
  u16* hT = (u16*)(ws + OFF_HT);
  u32* bitsT = (u32*)(ws + OFF_BITS);

  k_pack<<<(BB * NN) / 4, 256, 0, stream>>>(adj, bitsT);
  k_proj<<<(BB * NN) / 16, 256, 0, stream>>>(x, W, a, hT, e_src, PQv);
  k_attn<<<BB * NH * 32, 256, 0, stream>>>(hT, e_src, PQv, bitsT, out);
}